// Round 1
// baseline (710.915 us; speedup 1.0000x reference)
//
#include <hip/hip_runtime.h>
#include <cstdint>

// Problem constants (B,T from setup_inputs; L == T)
#define B_DIM 256
#define T_DIM 32768
#define L_DIM 32768

typedef __attribute__((ext_vector_type(8))) short short8;
typedef __attribute__((ext_vector_type(4))) float floatx4;

__device__ __forceinline__ unsigned short f2bf(float f) {
  union { float f; uint32_t u; } c; c.f = f;
  uint32_t u = c.u;
  u += 0x7FFFu + ((u >> 16) & 1u);   // round-to-nearest-even
  return (unsigned short)(u >> 16);
}

// Pass 1: x fp32 -> bf16 (row-major [256][32768])
__global__ void cvt_x_bf16(const float* __restrict__ x, unsigned short* __restrict__ o) {
  int i = blockIdx.x * blockDim.x + threadIdx.x;   // over 2,097,152 float4 chunks
  float4 v = ((const float4*)x)[i];
  ushort4 r;
  r.x = f2bf(v.x); r.y = f2bf(v.y); r.z = f2bf(v.z); r.w = f2bf(v.w);
  ((ushort4*)o)[i] = r;
}

// Pass 2: build the 512 distinct Toeplitz B-tiles.
// Bt[si][n][k] (n in [0,128), k in [0,64)) = filt[(si-1)*64 + n - k] masked to >=0.
// Layout [n][k] is exactly the LDS layout the MFMA B-operand fragment reads.
__global__ void build_bt(const float* __restrict__ filt, unsigned short* __restrict__ bt) {
  int idx = blockIdx.x * 256 + threadIdx.x;  // [0, 512*8192)
  int k  = idx & 63;
  int n  = (idx >> 6) & 127;
  int si = idx >> 13;                        // 0..511, shift s = (si-1)*64
  int d  = (si - 1) * 64 + n - k;            // max d = 32767, never >= L
  float v = (d >= 0) ? filt[d] : 0.0f;
  bt[idx] = f2bf(v);
}

// Main GEMM: Y[m,n] = sum_k X[m,k] * filt[n-k]  (k <= n)
// 128x128 output tile per block, BK=64, 4 waves in 2x2, each wave 64x64 via
// 4x4 grid of 16x16x32 bf16 MFMA. m97-style: global_load_lds width-16 staging,
// 2-barrier K loop.
__global__ __launch_bounds__(256, 2) void conv_gemm(
    const unsigned short* __restrict__ Xbf,
    const unsigned short* __restrict__ Bt,
    float* __restrict__ Y) {
  __shared__ unsigned short As[128 * 64];  // [row m][k]
  __shared__ unsigned short Bs[128 * 64];  // [col n][k]

  const int b  = blockIdx.x;
  const int mi = b & 1;
  const int ni = 255 - (b >> 1);     // big-K blocks dispatch first
  const int m0 = mi * 128;
  const int n0 = ni * 128;
  const int niter = 2 * ni + 2;      // k0 = 0..n0+64 step 64 covers k < n0+128

  const int tid  = threadIdx.x;
  const int w    = tid >> 6;         // wave id 0..3
  const int lane = tid & 63;
  const int qlo  = lane & 15;
  const int qhi  = lane >> 4;
  const int wr   = w >> 1;           // wave row (0..1) -> 64 rows
  const int wc   = w & 1;            // wave col (0..1) -> 64 cols

  floatx4 acc[4][4];
  #pragma unroll
  for (int i = 0; i < 4; ++i)
    #pragma unroll
    for (int j = 0; j < 4; ++j)
      acc[i][j] = (floatx4){0.f, 0.f, 0.f, 0.f};

  // staging geometry: each global_load_lds covers 8 rows x 64 cols (1 KiB/wave)
  const int a_r = w * 32 + (lane >> 3);   // + q*8
  const int a_c = (lane & 7) * 8;

  for (int it = 0; it < niter; ++it) {
    const int k0 = it * 64;
    const int si = 2 * ni + 1 - it;       // shift tile index, 0..511
    const unsigned short* gB = Bt + si * 8192 + w * 2048 + lane * 8;
    #pragma unroll
    for (int q = 0; q < 4; ++q) {
      const unsigned short* gA = Xbf + (m0 + a_r + q * 8) * T_DIM + k0 + a_c;
      __builtin_amdgcn_global_load_lds(
          (const __attribute__((address_space(1))) uint32_t*)gA,
          (__attribute__((address_space(3))) uint32_t*)&As[(w * 32 + q * 8) * 64],
          16, 0, 0);
      __builtin_amdgcn_global_load_lds(
          (const __attribute__((address_space(1))) uint32_t*)(gB + q * 512),
          (__attribute__((address_space(3))) uint32_t*)&Bs[(w * 32 + q * 8) * 64],
          16, 0, 0);
    }
    __syncthreads();

    #pragma unroll
    for (int ks = 0; ks < 2; ++ks) {
      short8 a[4], bb[4];
      #pragma unroll
      for (int im = 0; im < 4; ++im)
        a[im] = *(const short8*)&As[(wr * 64 + im * 16 + qlo) * 64 + ks * 32 + qhi * 8];
      #pragma unroll
      for (int in = 0; in < 4; ++in)
        bb[in] = *(const short8*)&Bs[(wc * 64 + in * 16 + qlo) * 64 + ks * 32 + qhi * 8];
      #pragma unroll
      for (int im = 0; im < 4; ++im)
        #pragma unroll
        for (int in = 0; in < 4; ++in)
          acc[im][in] = __builtin_amdgcn_mfma_f32_16x16x32_bf16(a[im], bb[in], acc[im][in], 0, 0, 0);
    }
    __syncthreads();
  }

  // epilogue: C/D layout col=lane&15, row=(lane>>4)*4+reg
  #pragma unroll
  for (int im = 0; im < 4; ++im) {
    #pragma unroll
    for (int in = 0; in < 4; ++in) {
      const int col = n0 + wc * 64 + in * 16 + qlo;
      #pragma unroll
      for (int r = 0; r < 4; ++r) {
        const int row = m0 + wr * 64 + im * 16 + qhi * 4 + r;
        Y[row * T_DIM + col] = acc[im][in][r];
      }
    }
  }
}

extern "C" void kernel_launch(void* const* d_in, const int* in_sizes, int n_in,
                              void* d_out, int out_size, void* d_ws, size_t ws_size,
                              hipStream_t stream) {
  const float* x    = (const float*)d_in[0];   // [256][32768] fp32
  const float* filt = (const float*)d_in[1];   // [1][32768]  fp32
  float* Y = (float*)d_out;                    // [256][32768] fp32

  unsigned short* Xbf = (unsigned short*)d_ws;                     // 16 MiB
  unsigned short* Bt  = Xbf + (size_t)B_DIM * T_DIM;               // 8 MiB

  hipLaunchKernelGGL(cvt_x_bf16, dim3(8192), dim3(256), 0, stream, x, Xbf);
  hipLaunchKernelGGL(build_bt,  dim3(16384), dim3(256), 0, stream, filt, Bt);
  hipLaunchKernelGGL(conv_gemm, dim3(512),   dim3(256), 0, stream, Xbf, Bt, Y);
}

// Round 2
// 387.491 us; speedup vs baseline: 1.8347x; 1.8347x over previous
//
#include <hip/hip_runtime.h>
#include <cstdint>

#define B_DIM 256
#define T_DIM 32768
#define L_DIM 32768

typedef __attribute__((ext_vector_type(8))) short short8;
typedef __attribute__((ext_vector_type(4))) float floatx4;

__device__ __forceinline__ unsigned short f2bf(float f) {
  union { float f; uint32_t u; } c; c.f = f;
  uint32_t u = c.u;
  u += 0x7FFFu + ((u >> 16) & 1u);   // round-to-nearest-even
  return (unsigned short)(u >> 16);
}

// Pass 1: x fp32 -> bf16 (row-major [256][32768])
__global__ void cvt_x_bf16(const float* __restrict__ x, unsigned short* __restrict__ o) {
  int i = blockIdx.x * blockDim.x + threadIdx.x;
  float4 v = ((const float4*)x)[i];
  ushort4 r;
  r.x = f2bf(v.x); r.y = f2bf(v.y); r.z = f2bf(v.z); r.w = f2bf(v.w);
  ((ushort4*)o)[i] = r;
}

// Pass 2: 512 distinct Toeplitz B-tiles. Bt[si][n][k] = filt[(si-1)*64 + n - k], d>=0.
__global__ void build_bt(const float* __restrict__ filt, unsigned short* __restrict__ bt) {
  int idx = blockIdx.x * 256 + threadIdx.x;
  int k  = idx & 63;
  int n  = (idx >> 6) & 127;
  int si = idx >> 13;
  int d  = (si - 1) * 64 + n - k;
  float v = (d >= 0) ? filt[d] : 0.0f;
  bt[idx] = f2bf(v);
}

// Pass 3: zero Y (harness poisons d_out; split-K accumulates atomically)
__global__ void zero_y(float* __restrict__ Y) {
  int i = blockIdx.x * 256 + threadIdx.x;
  ((float4*)Y)[i] = make_float4(0.f, 0.f, 0.f, 0.f);
}

// Main split-K GEMM. Work units: each (mi, ni) tile's niter=2ni+2 K-iters cut
// into chunks of <=64 iters. chunks(ni) = ceil((ni+1)/32) = g for
// ni in [32(g-1), 32g).  Units per mi-half: sum = 1152; total 2304.
// Unit decode: group g occupies [16g(g-1), 16g(g-1)+32g).
__global__ __launch_bounds__(256, 4) void conv_gemm_sk(
    const unsigned short* __restrict__ Xbf,
    const unsigned short* __restrict__ Bt,
    float* __restrict__ Y) {
  __shared__ unsigned short As[128 * 64];  // [row m][k], 16B chunks XOR-swizzled
  __shared__ unsigned short Bs[128 * 64];  // [col n][k], same swizzle

  // ---- decode work unit (big-K units dispatch first) ----
  int u = 2303 - blockIdx.x;
  int mi = 0;
  if (u >= 1152) { mi = 1; u -= 1152; }
  int g = 1;
  while (u >= 16 * g * (g - 1) + 32 * g) ++g;   // g in 1..8
  const int r0 = u - 16 * g * (g - 1);
  const int t  = r0 / g;
  const int c  = r0 - t * g;
  const int ni = (g - 1) * 32 + t;
  const int m0 = mi * 128;
  const int n0 = ni * 128;
  const int it0 = c * 64;
  const int it1 = min((c + 1) * 64, 2 * ni + 2);

  const int tid  = threadIdx.x;
  const int w    = tid >> 6;
  const int lane = tid & 63;
  const int qlo  = lane & 15;
  const int qhi  = lane >> 4;
  const int wr   = w >> 1;
  const int wc   = w & 1;

  floatx4 acc[4][4];
  #pragma unroll
  for (int i = 0; i < 4; ++i)
    #pragma unroll
    for (int j2 = 0; j2 < 4; ++j2)
      acc[i][j2] = (floatx4){0.f, 0.f, 0.f, 0.f};

  // staging geometry: lane l covers row r8=l>>3 (of 8), swizzled chunk j=p^r8
  const int r8 = lane >> 3;
  const int p  = lane & 7;
  const int sj = p ^ r8;            // source 16B-chunk index after swizzle
  const int q3 = qlo & 7;

  for (int it = it0; it < it1; ++it) {
    const int k0 = it * 64;
    const int si = 2 * ni + 1 - it;
    #pragma unroll
    for (int q = 0; q < 4; ++q) {
      const int R = w * 32 + q * 8 + r8;        // absolute tile row this lane loads
      const unsigned short* gA = Xbf + (size_t)(m0 + R) * T_DIM + k0 + sj * 8;
      const unsigned short* gB = Bt + si * 8192 + R * 64 + sj * 8;
      __builtin_amdgcn_global_load_lds(
          (const __attribute__((address_space(1))) uint32_t*)gA,
          (__attribute__((address_space(3))) uint32_t*)&As[(w * 32 + q * 8) * 64],
          16, 0, 0);
      __builtin_amdgcn_global_load_lds(
          (const __attribute__((address_space(1))) uint32_t*)gB,
          (__attribute__((address_space(3))) uint32_t*)&Bs[(w * 32 + q * 8) * 64],
          16, 0, 0);
    }
    __syncthreads();

    #pragma unroll
    for (int ks = 0; ks < 2; ++ks) {
      short8 a[4], bb[4];
      #pragma unroll
      for (int im = 0; im < 4; ++im) {
        const int R = wr * 64 + im * 16 + qlo;
        a[im] = *(const short8*)&As[R * 64 + (((ks * 4 + qhi) ^ q3) << 3)];
      }
      #pragma unroll
      for (int in = 0; in < 4; ++in) {
        const int R = wc * 64 + in * 16 + qlo;
        bb[in] = *(const short8*)&Bs[R * 64 + (((ks * 4 + qhi) ^ q3) << 3)];
      }
      #pragma unroll
      for (int im = 0; im < 4; ++im)
        #pragma unroll
        for (int in = 0; in < 4; ++in)
          acc[im][in] = __builtin_amdgcn_mfma_f32_16x16x32_bf16(a[im], bb[in], acc[im][in], 0, 0, 0);
    }
    __syncthreads();
  }

  // epilogue: atomic accumulate partial tile. C/D: col=lane&15, row=(lane>>4)*4+reg
  #pragma unroll
  for (int im = 0; im < 4; ++im) {
    #pragma unroll
    for (int in = 0; in < 4; ++in) {
      const int col = n0 + wc * 64 + in * 16 + qlo;
      #pragma unroll
      for (int r = 0; r < 4; ++r) {
        const int row = m0 + wr * 64 + im * 16 + qhi * 4 + r;
        unsafeAtomicAdd(&Y[(size_t)row * T_DIM + col], acc[im][in][r]);
      }
    }
  }
}

extern "C" void kernel_launch(void* const* d_in, const int* in_sizes, int n_in,
                              void* d_out, int out_size, void* d_ws, size_t ws_size,
                              hipStream_t stream) {
  const float* x    = (const float*)d_in[0];   // [256][32768] fp32
  const float* filt = (const float*)d_in[1];   // [1][32768]  fp32
  float* Y = (float*)d_out;                    // [256][32768] fp32

  unsigned short* Xbf = (unsigned short*)d_ws;                 // 16 MiB
  unsigned short* Bt  = Xbf + (size_t)B_DIM * T_DIM;           // 8 MiB

  hipLaunchKernelGGL(cvt_x_bf16, dim3(8192), dim3(256), 0, stream, x, Xbf);
  hipLaunchKernelGGL(build_bt,  dim3(16384), dim3(256), 0, stream, filt, Bt);
  hipLaunchKernelGGL(zero_y,    dim3(8192),  dim3(256), 0, stream, Y);
  hipLaunchKernelGGL(conv_gemm_sk, dim3(2304), dim3(256), 0, stream, Xbf, Bt, Y);
}

// Round 3
// 264.937 us; speedup vs baseline: 2.6833x; 1.4626x over previous
//
#include <hip/hip_runtime.h>
#include <cstdint>

typedef __attribute__((ext_vector_type(8))) short short8;
typedef __attribute__((ext_vector_type(4))) float floatx4;

__device__ __forceinline__ unsigned short f2bf(float f) {
  union { float f; uint32_t u; } c; c.f = f;
  uint32_t u = c.u;
  u += 0x7FFFu + ((u >> 16) & 1u);   // RNE
  return (unsigned short)(u >> 16);
}
__device__ __forceinline__ uint32_t packbf(float re, float im) {
  return (uint32_t)f2bf(re) | ((uint32_t)f2bf(im) << 16);
}

// ---------------------------------------------------------------------------
// Four-step DFT convolution, N = 65536 = 256 x 256, t = c + 256 r, k = k1 + 256 k2.
// z_s = x[2s] + i x[2s+1].  All 256-pt DFT stages are real bf16 MFMA GEMMs via
// the 2x2 rotation embedding: A'[2m][2k]=cos,[2k+1]=-+sin; A'[2m+1][2k]=+-sin,[2k+1]=cos.
// ---------------------------------------------------------------------------

// Tables: A1 [512x256] E-(k1 r/256); A2 [512x512] E-(k2 c/256);
// A3 [512x512] rows=2c+d cols=2k2+e, E+(k2 c/256); A4 [256x512] rows=2r+d cols=2k1+e, E+(k1 r/256);
// T[65536] = (cos, sin)(2 pi idx / 65536).
__global__ void prep_tables(unsigned short* __restrict__ A1,
                            unsigned short* __restrict__ A2,
                            unsigned short* __restrict__ A3,
                            unsigned short* __restrict__ A4,
                            float2* __restrict__ T) {
  int idx = blockIdx.x * 256 + threadIdx.x;
  const float w256 = 6.283185307179586f / 256.0f;
  if (idx < 131072) {                       // A1, E-
    int col = idx & 255, row = idx >> 8;
    int k1 = row >> 1, d = row & 1, r = col >> 1, e = col & 1;
    float th = (float)((k1 * r) & 255) * w256;
    float cs = cosf(th), sn = sinf(th);
    A1[idx] = f2bf(d == 0 ? (e == 0 ? cs : sn) : (e == 0 ? -sn : cs));
  } else if (idx < 393216) {                // A2, E-
    int j = idx - 131072;
    int col = j & 511, row = j >> 9;
    int k2 = row >> 1, d = row & 1, cc = col >> 1, e = col & 1;
    float th = (float)((k2 * cc) & 255) * w256;
    float cs = cosf(th), sn = sinf(th);
    A2[j] = f2bf(d == 0 ? (e == 0 ? cs : sn) : (e == 0 ? -sn : cs));
  } else if (idx < 655360) {                // A3, E+
    int j = idx - 393216;
    int col = j & 511, row = j >> 9;
    int cc = row >> 1, d = row & 1, k2 = col >> 1, e = col & 1;
    float th = (float)((k2 * cc) & 255) * w256;
    float cs = cosf(th), sn = sinf(th);
    A3[j] = f2bf(d == 0 ? (e == 0 ? cs : -sn) : (e == 0 ? sn : cs));
  } else if (idx < 786432) {                // A4, E+
    int j = idx - 655360;
    int col = j & 511, row = j >> 9;
    int r = row >> 1, d = row & 1, k1 = col >> 1, e = col & 1;
    float th = (float)((k1 * r) & 255) * w256;
    float cs = cosf(th), sn = sinf(th);
    A4[j] = f2bf(d == 0 ? (e == 0 ? cs : -sn) : (e == 0 ? sn : cs));
  } else if (idx < 851968) {                // T
    int j = idx - 786432;
    float th = (float)j * (6.283185307179586f / 65536.0f);
    T[j] = make_float2(cosf(th), sinf(th));
  }
}

// Z'[(s*256+c)][r packed u32: lo=bf16(x[2s]), hi=bf16(x[2s+1])], r<128. block=(s, r-half)
__global__ __launch_bounds__(256) void prep_z(const float* __restrict__ x,
                                              uint32_t* __restrict__ Zp) {
  __shared__ uint32_t lds[64 * 256];
  const int s = blockIdx.x >> 1, rh = blockIdx.x & 1;
  const float* x0 = x + (size_t)(2 * s) * 32768 + rh * 16384;
  const float* x1 = x0 + 32768;
  const int tid = threadIdx.x;
  for (int i = 0; i < 64; ++i) {
    int t = i * 256 + tid;                  // c = tid, r_local = i (coalesced)
    lds[i * 256 + tid] = (uint32_t)f2bf(x0[t]) | ((uint32_t)f2bf(x1[t]) << 16);
  }
  uint32_t* dst = Zp + (size_t)(s * 256 + tid) * 128 + rh * 64;
  for (int i = 0; i < 64; i += 4) {
    uint4 v;
    v.x = lds[(i + 0) * 256 + tid];
    v.y = lds[(i + 1) * 256 + tid];
    v.z = lds[(i + 2) * 256 + tid];
    v.w = lds[(i + 3) * 256 + tid];
    *(uint4*)(dst + i) = v;
  }
}

// Gw[k1][c] = (sum_{r<128} filt[c+256r] E-(k1 r/256)) * E-(k1 c/65536)   (fp32)
__global__ void prep_wa(const float* __restrict__ filt, const float2* __restrict__ T,
                        float2* __restrict__ Gw) {
  int idx = blockIdx.x * 256 + threadIdx.x;
  int k1 = idx >> 8, c = idx & 255;
  float ar = 0.f, ai = 0.f;
  for (int r = 0; r < 128; ++r) {
    float v = filt[c + 256 * r];
    float2 t = T[((k1 * r) & 255) << 8];
    ar += v * t.x; ai -= v * t.y;           // v * (cos - i sin)
  }
  float2 t = T[(k1 * c) & 65535];
  Gw[idx] = make_float2(ar * t.x + ai * t.y, ai * t.x - ar * t.y);
}

// What[k1][k2] = sum_c Gw[k1][c] E-(k2 c/256)   (fp32)
__global__ void prep_wb(const float2* __restrict__ Gw, const float2* __restrict__ T,
                        float2* __restrict__ Wt) {
  int idx = blockIdx.x * 256 + threadIdx.x;
  int k1 = idx >> 8, k2 = idx & 255;
  float ar = 0.f, ai = 0.f;
  for (int c = 0; c < 256; ++c) {
    float2 g = Gw[(k1 << 8) + c];
    float2 t = T[((k2 * c) & 255) << 8];
    ar += g.x * t.x + g.y * t.y;            // g * (cos - i sin)
    ai += g.y * t.x - g.x * t.y;
  }
  Wt[idx] = make_float2(ar, ai);
}

// One DFT stage = real bf16 GEMM C[m'][n] = sum_k' A'[m'][k'] B[n][k'] + mode epilogue.
// MODE 1: *E-(k1 c/65536), write G2[(s,k1)][c].   MODE 2: *What, write P[(s,k1)][k2].
// MODE 3: *E+(k1 c/65536), write H2[(s,c)][k1].   MODE 4: write y (scale 1/65536).
template <int MODE, int KITERS>
__global__ __launch_bounds__(256, 4) void dft_stage(
    const unsigned short* __restrict__ Af,
    const unsigned short* __restrict__ Bd,
    uint32_t* __restrict__ outp,
    float* __restrict__ yout,
    const float2* __restrict__ Tt,
    const float2* __restrict__ Wt) {
  __shared__ unsigned short As[128 * 64];
  __shared__ unsigned short Bs[128 * 64];
  constexpr int KP = KITERS * 64;

  const int mt = blockIdx.x >> 8;
  const int nt = blockIdx.x & 255;
  const int m0 = mt * 128, n0 = nt * 128;

  const int tid = threadIdx.x;
  const int w = tid >> 6, lane = tid & 63;
  const int qlo = lane & 15, qhi = lane >> 4;
  const int wr = w >> 1, wc = w & 1;

  floatx4 acc[4][4];
  #pragma unroll
  for (int i = 0; i < 4; ++i)
    #pragma unroll
    for (int j = 0; j < 4; ++j) acc[i][j] = (floatx4){0.f, 0.f, 0.f, 0.f};

  const int r8 = lane >> 3, pl = lane & 7, sj = pl ^ r8, q3 = qlo & 7;

  for (int it = 0; it < KITERS; ++it) {
    const int k0 = it * 64;
    #pragma unroll
    for (int q = 0; q < 4; ++q) {
      const int R = w * 32 + q * 8 + r8;
      const unsigned short* gA = Af + (size_t)(m0 + R) * KP + k0 + sj * 8;
      const unsigned short* gB = Bd + (size_t)(n0 + R) * KP + k0 + sj * 8;
      __builtin_amdgcn_global_load_lds(
          (const __attribute__((address_space(1))) uint32_t*)gA,
          (__attribute__((address_space(3))) uint32_t*)&As[(w * 32 + q * 8) * 64], 16, 0, 0);
      __builtin_amdgcn_global_load_lds(
          (const __attribute__((address_space(1))) uint32_t*)gB,
          (__attribute__((address_space(3))) uint32_t*)&Bs[(w * 32 + q * 8) * 64], 16, 0, 0);
    }
    __syncthreads();
    #pragma unroll
    for (int ks = 0; ks < 2; ++ks) {
      short8 a[4], bb[4];
      #pragma unroll
      for (int im = 0; im < 4; ++im) {
        const int R = wr * 64 + im * 16 + qlo;
        a[im] = *(const short8*)&As[R * 64 + (((ks * 4 + qhi) ^ q3) << 3)];
      }
      #pragma unroll
      for (int in = 0; in < 4; ++in) {
        const int R = wc * 64 + in * 16 + qlo;
        bb[in] = *(const short8*)&Bs[R * 64 + (((ks * 4 + qhi) ^ q3) << 3)];
      }
      #pragma unroll
      for (int im = 0; im < 4; ++im)
        #pragma unroll
        for (int in = 0; in < 4; ++in)
          acc[im][in] = __builtin_amdgcn_mfma_f32_16x16x32_bf16(a[im], bb[in], acc[im][in], 0, 0, 0);
    }
    __syncthreads();
  }

  // epilogue: C rows = interleaved (re,im); the complex pair sits in one lane.
  #pragma unroll
  for (int im = 0; im < 4; ++im) {
    const int mC0 = (m0 + wr * 64 + im * 16 + qhi * 4) >> 1;
    #pragma unroll
    for (int in = 0; in < 4; ++in) {
      const int col = n0 + wc * 64 + in * 16 + qlo;
      const int s_idx = col >> 8, cloc = col & 255;
      #pragma unroll
      for (int pp = 0; pp < 2; ++pp) {
        const int mC = mC0 + pp;
        float re = acc[im][in][2 * pp], iv = acc[im][in][2 * pp + 1];
        if (MODE == 1) {
          float2 t = Tt[(mC * cloc) & 65535];                 // E-: (c - i s)
          float r2 = re * t.x + iv * t.y, i2 = iv * t.x - re * t.y;
          outp[(size_t)((s_idx << 8) + mC) * 256 + cloc] = packbf(r2, i2);
        } else if (MODE == 2) {
          float2 wv = Wt[(cloc << 8) + mC];                   // * What[k1][k2]
          float r2 = re * wv.x - iv * wv.y, i2 = re * wv.y + iv * wv.x;
          outp[(size_t)((s_idx << 8) + cloc) * 256 + mC] = packbf(r2, i2);
        } else if (MODE == 3) {
          float2 t = Tt[(mC * cloc) & 65535];                 // E+: (c + i s)
          float r2 = re * t.x - iv * t.y, i2 = iv * t.x + re * t.y;
          outp[(size_t)((s_idx << 8) + mC) * 256 + cloc] = packbf(r2, i2);
        } else {
          const float sc = 1.0f / 65536.0f;
          float* y0 = yout + ((size_t)s_idx << 16) + (mC << 8) + cloc;
          y0[0] = re * sc;        // y[2s][c+256r]
          y0[32768] = iv * sc;    // y[2s+1][c+256r]
        }
      }
    }
  }
}

extern "C" void kernel_launch(void* const* d_in, const int* in_sizes, int n_in,
                              void* d_out, int out_size, void* d_ws, size_t ws_size,
                              hipStream_t stream) {
  const float* x = (const float*)d_in[0];     // [256][32768] fp32
  const float* filt = (const float*)d_in[1];  // [1][32768] fp32
  float* Y = (float*)d_out;                   // [256][32768] fp32

  char* ws = (char*)d_ws;
  unsigned short* A1 = (unsigned short*)(ws + 0);              // 256 KB
  unsigned short* A2 = (unsigned short*)(ws + (256u << 10));   // 512 KB
  unsigned short* A3 = (unsigned short*)(ws + (768u << 10));   // 512 KB
  unsigned short* A4 = (unsigned short*)(ws + (1280u << 10));  // 256 KB
  float2* T  = (float2*)(ws + (1536u << 10));                  // 512 KB
  float2* Gw = (float2*)(ws + (2048u << 10));                  // 512 KB
  float2* Wt = (float2*)(ws + (2560u << 10));                  // 512 KB
  unsigned short* Zp = (unsigned short*)(ws + (3u << 20));     // 16 MB  [3,19)
  unsigned short* G2 = (unsigned short*)(ws + 19922944u);      // 32 MB  [19,51)
  unsigned short* P  = (unsigned short*)(ws + 53477376u);      // 32 MB  [51,83)
  unsigned short* H2 = (unsigned short*)(ws + (3u << 20));     // 32 MB, reuses Zp+G2 (dead)

  hipLaunchKernelGGL(prep_tables, dim3(3328), dim3(256), 0, stream, A1, A2, A3, A4, T);
  hipLaunchKernelGGL(prep_z, dim3(256), dim3(256), 0, stream, x, (uint32_t*)Zp);
  hipLaunchKernelGGL(prep_wa, dim3(256), dim3(256), 0, stream, filt, T, Gw);
  hipLaunchKernelGGL(prep_wb, dim3(256), dim3(256), 0, stream, Gw, T, Wt);

  hipLaunchKernelGGL((dft_stage<1, 4>), dim3(1024), dim3(256), 0, stream,
                     A1, Zp, (uint32_t*)G2, (float*)nullptr, T, (const float2*)nullptr);
  hipLaunchKernelGGL((dft_stage<2, 8>), dim3(1024), dim3(256), 0, stream,
                     A2, G2, (uint32_t*)P, (float*)nullptr, (const float2*)nullptr, Wt);
  hipLaunchKernelGGL((dft_stage<3, 8>), dim3(1024), dim3(256), 0, stream,
                     A3, P, (uint32_t*)H2, (float*)nullptr, T, (const float2*)nullptr);
  hipLaunchKernelGGL((dft_stage<4, 8>), dim3(512), dim3(256), 0, stream,
                     A4, H2, (uint32_t*)nullptr, Y, (const float2*)nullptr, (const float2*)nullptr);
}

// Round 4
// 194.022 us; speedup vs baseline: 3.6641x; 1.3655x over previous
//
#include <hip/hip_runtime.h>
#include <cstdint>

typedef __attribute__((ext_vector_type(8))) short short8;
typedef __attribute__((ext_vector_type(4))) float floatx4;

#define TWO_PI 6.283185307179586f

__device__ __forceinline__ unsigned short f2bf(float f) {
  union { float f; uint32_t u; } c; c.f = f;
  uint32_t u = c.u;
  u += 0x7FFFu + ((u >> 16) & 1u);   // RNE
  return (unsigned short)(u >> 16);
}
__device__ __forceinline__ uint32_t packbf(float re, float im) {
  return (uint32_t)f2bf(re) | ((uint32_t)f2bf(im) << 16);
}

// ---------------------------------------------------------------------------
// Four-step DFT convolution, N = 65536 = 256 x 256, t = c + 256 r, k = k1 + 256 k2.
// z_s = x[2s] + i x[2s+1].  All 256-pt DFT stages are real bf16 MFMA GEMMs via
// the 2x2 rotation embedding.
// ---------------------------------------------------------------------------

// Merged prep: blocks [0,3072) build A1..A4; [3072,4096) transpose/pack x->Zp;
// [4096,4352) compute Gw[k1][c] (stage-1+twiddle of filter, fp32).
__global__ __launch_bounds__(256) void prep_all(
    const float* __restrict__ x, const float* __restrict__ filt,
    unsigned short* __restrict__ A1, unsigned short* __restrict__ A2,
    unsigned short* __restrict__ A3, unsigned short* __restrict__ A4,
    uint32_t* __restrict__ Zp, float2* __restrict__ Gw) {
  const int bid = blockIdx.x;
  const int tid = threadIdx.x;
  const float w256 = TWO_PI / 256.0f;
  if (bid < 3072) {
    int idx = bid * 256 + tid;
    if (idx < 131072) {                       // A1 [512x256], E-(k1 r/256)
      int col = idx & 255, row = idx >> 8;
      int k1 = row >> 1, d = row & 1, r = col >> 1, e = col & 1;
      float th = (float)((k1 * r) & 255) * w256;
      float sn, cs; __sincosf(th, &sn, &cs);
      A1[idx] = f2bf(d == 0 ? (e == 0 ? cs : sn) : (e == 0 ? -sn : cs));
    } else if (idx < 393216) {                // A2 [512x512], E-(k2 c/256)
      int j = idx - 131072;
      int col = j & 511, row = j >> 9;
      int k2 = row >> 1, d = row & 1, cc = col >> 1, e = col & 1;
      float th = (float)((k2 * cc) & 255) * w256;
      float sn, cs; __sincosf(th, &sn, &cs);
      A2[j] = f2bf(d == 0 ? (e == 0 ? cs : sn) : (e == 0 ? -sn : cs));
    } else if (idx < 655360) {                // A3 [512x512], rows 2c+d, E+(k2 c/256)
      int j = idx - 393216;
      int col = j & 511, row = j >> 9;
      int cc = row >> 1, d = row & 1, k2 = col >> 1, e = col & 1;
      float th = (float)((k2 * cc) & 255) * w256;
      float sn, cs; __sincosf(th, &sn, &cs);
      A3[j] = f2bf(d == 0 ? (e == 0 ? cs : -sn) : (e == 0 ? sn : cs));
    } else {                                  // A4 [256x512], rows 2r+d, E+(k1 r/256)
      int j = idx - 655360;
      int col = j & 511, row = j >> 9;
      int r = row >> 1, d = row & 1, k1 = col >> 1, e = col & 1;
      float th = (float)((k1 * r) & 255) * w256;
      float sn, cs; __sincosf(th, &sn, &cs);
      A4[j] = f2bf(d == 0 ? (e == 0 ? cs : -sn) : (e == 0 ? sn : cs));
    }
  } else if (bid < 4096) {                    // Zp[(s*256+c)][r] packed bf16 pair
    int b2 = bid - 3072;                      // 1024 blocks: (s, r-chunk of 16)
    int s = b2 >> 3, rq = b2 & 7;
    const float* x0 = x + (size_t)(2 * s) * 32768;
    const float* x1 = x0 + 32768;
    uint32_t v[16];
    #pragma unroll
    for (int rr = 0; rr < 16; ++rr) {
      int t = tid + 256 * (rq * 16 + rr);
      v[rr] = (uint32_t)f2bf(x0[t]) | ((uint32_t)f2bf(x1[t]) << 16);
    }
    uint32_t* dst = Zp + (size_t)(s * 256 + tid) * 128 + rq * 16;
    #pragma unroll
    for (int j = 0; j < 16; j += 4)
      *(uint4*)(dst + j) = make_uint4(v[j], v[j + 1], v[j + 2], v[j + 3]);
  } else {                                    // Gw[k1][c], fp32
    int k1 = bid - 4096, c = tid;
    float ar = 0.f, ai = 0.f;
    for (int r = 0; r < 128; ++r) {
      float v = filt[c + 256 * r];
      float th = (float)((k1 * r) & 255) * w256;
      float sn, cs; __sincosf(th, &sn, &cs);
      ar += v * cs; ai -= v * sn;
    }
    float th = (float)((k1 * c) & 65535) * (TWO_PI / 65536.0f);
    float sn, cs; __sincosf(th, &sn, &cs);
    Gw[(k1 << 8) + c] = make_float2(ar * cs + ai * sn, ai * cs - ar * sn);
  }
}

// WtT[k2][k1] = sum_c Gw[k1][c] E-(k2 c/256)   (fp32, TRANSPOSED for coalesced epilogue)
__global__ __launch_bounds__(256) void prep_wb(const float2* __restrict__ Gw,
                                               float2* __restrict__ WtT) {
  int k1 = blockIdx.x, k2 = threadIdx.x;
  float ar = 0.f, ai = 0.f;
  for (int c = 0; c < 256; ++c) {
    float2 g = Gw[(k1 << 8) + c];             // wave-uniform broadcast
    float th = (float)((k2 * c) & 255) * (TWO_PI / 256.0f);
    float sn, cs; __sincosf(th, &sn, &cs);
    ar += g.x * cs + g.y * sn;
    ai += g.y * cs - g.x * sn;
  }
  WtT[(k2 << 8) + k1] = make_float2(ar, ai);
}

// One DFT stage = real bf16 GEMM C[m][n] = sum_k A[m][k] B[n][k] + mode epilogue.
// Double-buffered LDS staging, one barrier per K-iter.
// MODE 1: *E-(k1 c/65536) -> G2[(s,k1)][c].   MODE 2: *WtT -> P[(s,k1)][k2] (LDS transpose).
// MODE 3: *E+(k1 c/65536) -> H2[(s,c)][k1].   MODE 4: write y (scale 1/65536).
template <int MODE, int KITERS>
__global__ __launch_bounds__(256, 2) void dft_stage(
    const unsigned short* __restrict__ Af,
    const unsigned short* __restrict__ Bd,
    uint32_t* __restrict__ outp,
    float* __restrict__ yout,
    const float2* __restrict__ WtT) {
  __shared__ unsigned short Sm[32768];        // As0|As1|Bs0|Bs1, 16 KB each
  constexpr int KP = KITERS * 64;

  const int mt = blockIdx.x >> 8;
  const int nt = blockIdx.x & 255;
  const int m0 = mt * 128, n0 = nt * 128;

  const int tid = threadIdx.x;
  const int w = tid >> 6, lane = tid & 63;
  const int qlo = lane & 15, qhi = lane >> 4;
  const int wr = w >> 1, wc = w & 1;
  const int r8 = lane >> 3, pl = lane & 7, sj = pl ^ r8, q3 = qlo & 7;

  floatx4 acc[4][4];
  #pragma unroll
  for (int i = 0; i < 4; ++i)
    #pragma unroll
    for (int j = 0; j < 4; ++j) acc[i][j] = (floatx4){0.f, 0.f, 0.f, 0.f};

  auto issue = [&](int it, int buf) {
    const int k0 = it * 64;
    unsigned short* Asb = Sm + buf * 8192;
    unsigned short* Bsb = Sm + 16384 + buf * 8192;
    #pragma unroll
    for (int q = 0; q < 4; ++q) {
      const int R = w * 32 + q * 8 + r8;
      const unsigned short* gA = Af + (size_t)(m0 + R) * KP + k0 + sj * 8;
      const unsigned short* gB = Bd + (size_t)(n0 + R) * KP + k0 + sj * 8;
      __builtin_amdgcn_global_load_lds(
          (const __attribute__((address_space(1))) uint32_t*)gA,
          (__attribute__((address_space(3))) uint32_t*)&Asb[(w * 32 + q * 8) * 64], 16, 0, 0);
      __builtin_amdgcn_global_load_lds(
          (const __attribute__((address_space(1))) uint32_t*)gB,
          (__attribute__((address_space(3))) uint32_t*)&Bsb[(w * 32 + q * 8) * 64], 16, 0, 0);
    }
  };

  issue(0, 0);
  for (int it = 0; it < KITERS; ++it) {
    __syncthreads();                          // drains prev iter's prefetch (vmcnt)
    if (it + 1 < KITERS) issue(it + 1, (it + 1) & 1);
    const unsigned short* Ab = Sm + (it & 1) * 8192;
    const unsigned short* Bb = Sm + 16384 + (it & 1) * 8192;
    #pragma unroll
    for (int ks = 0; ks < 2; ++ks) {
      short8 a[4], bb[4];
      #pragma unroll
      for (int im = 0; im < 4; ++im) {
        const int R = wr * 64 + im * 16 + qlo;
        a[im] = *(const short8*)&Ab[R * 64 + (((ks * 4 + qhi) ^ q3) << 3)];
      }
      #pragma unroll
      for (int in = 0; in < 4; ++in) {
        const int R = wc * 64 + in * 16 + qlo;
        bb[in] = *(const short8*)&Bb[R * 64 + (((ks * 4 + qhi) ^ q3) << 3)];
      }
      #pragma unroll
      for (int im = 0; im < 4; ++im)
        #pragma unroll
        for (int in = 0; in < 4; ++in)
          acc[im][in] = __builtin_amdgcn_mfma_f32_16x16x32_bf16(a[im], bb[in], acc[im][in], 0, 0, 0);
    }
  }

  const int s_idx = n0 >> 8;                  // block-constant (128 | 256)
  const int cl0 = n0 & 255;

  if (MODE == 2) {
    __syncthreads();                          // staging buffers now dead -> reuse
    uint32_t* Tr = (uint32_t*)Sm;             // [128 n][68 pad] u32
    #pragma unroll
    for (int im = 0; im < 4; ++im) {
      const int mloc = wr * 32 + im * 8 + qhi * 2;
      #pragma unroll
      for (int in = 0; in < 4; ++in) {
        const int nloc = wc * 64 + in * 16 + qlo;
        #pragma unroll
        for (int pp = 0; pp < 2; ++pp) {
          const int mC = (m0 >> 1) + mloc + pp;         // global k2
          float re = acc[im][in][2 * pp], iv = acc[im][in][2 * pp + 1];
          float2 wv = WtT[(mC << 8) + cl0 + nloc];      // coalesced (lanes->k1)
          float r2 = re * wv.x - iv * wv.y, i2 = re * wv.y + iv * wv.x;
          Tr[nloc * 68 + mloc + pp] = packbf(r2, i2);
        }
      }
    }
    __syncthreads();
    const int ln = tid >> 1, half = tid & 1;
    uint32_t* dst = outp + (size_t)((s_idx << 8) + cl0 + ln) * 256 + (m0 >> 1) + half * 32;
    const uint32_t* srcp = Tr + ln * 68 + half * 32;
    #pragma unroll
    for (int j = 0; j < 32; j += 4)
      *(uint4*)(dst + j) = *(const uint4*)(srcp + j);
    return;
  }

  #pragma unroll
  for (int im = 0; im < 4; ++im) {
    const int mloc = wr * 32 + im * 8 + qhi * 2;
    #pragma unroll
    for (int in = 0; in < 4; ++in) {
      const int nloc = wc * 64 + in * 16 + qlo;
      const int cloc = cl0 + nloc;
      #pragma unroll
      for (int pp = 0; pp < 2; ++pp) {
        const int mC = (m0 >> 1) + mloc + pp;
        float re = acc[im][in][2 * pp], iv = acc[im][in][2 * pp + 1];
        if (MODE == 1) {
          float th = (float)((mC * cloc) & 65535) * (TWO_PI / 65536.0f);
          float sn, cs; __sincosf(th, &sn, &cs);        // E-
          float r2 = re * cs + iv * sn, i2 = iv * cs - re * sn;
          outp[(size_t)((s_idx << 8) + mC) * 256 + cloc] = packbf(r2, i2);
        } else if (MODE == 3) {
          float th = (float)((mC * cloc) & 65535) * (TWO_PI / 65536.0f);
          float sn, cs; __sincosf(th, &sn, &cs);        // E+
          float r2 = re * cs - iv * sn, i2 = iv * cs + re * sn;
          outp[(size_t)((s_idx << 8) + mC) * 256 + cloc] = packbf(r2, i2);
        } else {                                        // MODE 4: final y
          const float sc = 1.0f / 65536.0f;
          float* y0 = yout + ((size_t)s_idx << 16) + (mC << 8) + cloc;
          y0[0] = re * sc;        // y[2s][c+256r]
          y0[32768] = iv * sc;    // y[2s+1][c+256r]
        }
      }
    }
  }
}

extern "C" void kernel_launch(void* const* d_in, const int* in_sizes, int n_in,
                              void* d_out, int out_size, void* d_ws, size_t ws_size,
                              hipStream_t stream) {
  const float* x = (const float*)d_in[0];     // [256][32768] fp32
  const float* filt = (const float*)d_in[1];  // [1][32768] fp32
  float* Y = (float*)d_out;                   // [256][32768] fp32

  char* ws = (char*)d_ws;
  unsigned short* A1 = (unsigned short*)(ws + 0);              // 256 KB
  unsigned short* A2 = (unsigned short*)(ws + 0x40000);        // 512 KB
  unsigned short* A3 = (unsigned short*)(ws + 0xC0000);        // 512 KB
  unsigned short* A4 = (unsigned short*)(ws + 0x140000);       // 256 KB
  float2* Gw  = (float2*)(ws + 0x180000);                      // 512 KB
  float2* WtT = (float2*)(ws + 0x200000);                      // 512 KB
  unsigned short* Zp = (unsigned short*)(ws + (3u << 20));     // 16 MB  [3,19)
  unsigned short* G2 = (unsigned short*)(ws + 19922944u);      // 32 MB  [19,51)
  unsigned short* P  = (unsigned short*)(ws + 53477376u);      // 32 MB  [51,83)
  unsigned short* H2 = (unsigned short*)(ws + (3u << 20));     // 32 MB, reuses Zp+G2 (dead)

  hipLaunchKernelGGL(prep_all, dim3(4352), dim3(256), 0, stream,
                     x, filt, A1, A2, A3, A4, (uint32_t*)Zp, Gw);
  hipLaunchKernelGGL(prep_wb, dim3(256), dim3(256), 0, stream, Gw, WtT);

  hipLaunchKernelGGL((dft_stage<1, 4>), dim3(1024), dim3(256), 0, stream,
                     A1, Zp, (uint32_t*)G2, (float*)nullptr, (const float2*)nullptr);
  hipLaunchKernelGGL((dft_stage<2, 8>), dim3(1024), dim3(256), 0, stream,
                     A2, G2, (uint32_t*)P, (float*)nullptr, WtT);
  hipLaunchKernelGGL((dft_stage<3, 8>), dim3(1024), dim3(256), 0, stream,
                     A3, P, (uint32_t*)H2, (float*)nullptr, (const float2*)nullptr);
  hipLaunchKernelGGL((dft_stage<4, 8>), dim3(512), dim3(256), 0, stream,
                     A4, H2, (uint32_t*)nullptr, Y, (const float2*)nullptr);
}